// Round 10
// baseline (555.014 us; speedup 1.0000x reference)
//
#include <hip/hip_runtime.h>

// LightGCN propagation on MI355X (gfx950).
//   h_{k+1}[r,:] = sum_{e: row[e]==r} val[e] * h_k[col[e],:]   D=32
//   out = (x + h1 + h2 + h3) / 4
//
// Round 10: R7 (LDS-staged records), R9 (bf16 gather, half the traffic and
// half the gather instrs) were all NEUTRAL at ~220 us, and every kernel is
// individually <43 us -> the pinned cost is launch/ramp/drain overhead of 9
// serialized dispatches + underfilled small passes, not inner loops.
// Fuse EVERYTHING into one persistent kernel: 256 blocks x 1024 thr
// (exactly 1 block/CU -> co-resident by construction), device-scope atomic
// grid barriers between phases:
//   P1 hist (196 chunk blocks) + cvt x->bf16 (all blocks)
//   P2 scan (block 0)       P3 multisplit scatter       P4 bucket row-sort
//   P5/P6/P7 spmm layers (R9's 4-lane bf16-gather register-accumulate)
// Phase internals are the proven R6/R9 code. 1 memset + 1 launch vs 9.

#define NN 100000
#define NE 1600000
#define DD 32
#define CHUNK 8192
#define NCHUNK ((NE + CHUNK - 1) / CHUNK)   // 196  (one chunk per block)
#define BROWS 128
#define NBKT ((NN + BROWS - 1) / BROWS)     // 782
#define GRID 256
#define TPB 1024

__device__ __forceinline__ unsigned f2bf(float f) {
    unsigned u = __float_as_uint(f);
    return (u + 0x7fffu + ((u >> 16) & 1u)) >> 16;   // RNE
}

// Device-scope sense-free barrier: one fresh counter per phase (memset to 0
// each call). Release-add on arrive, acquire-load spin, fences both sides.
__device__ __forceinline__ void grid_barrier(int* bar, int k) {
    __syncthreads();
    if (threadIdx.x == 0) {
        __threadfence();
        __hip_atomic_fetch_add(&bar[k], 1, __ATOMIC_RELEASE,
                               __HIP_MEMORY_SCOPE_AGENT);
        while (__hip_atomic_load(&bar[k], __ATOMIC_ACQUIRE,
                                 __HIP_MEMORY_SCOPE_AGENT) < GRID)
            __builtin_amdgcn_s_sleep(2);
        __threadfence();
    }
    __syncthreads();
}

// ---- spmm phase (R9 inner loop): 4-lane group/row, bf16 uint4 gather -----
template <int MODE>
__device__ __forceinline__ void spmm_phase(
    const int* __restrict__ row_ptr, const int2* __restrict__ edges,
    const uint4* __restrict__ hb4, uint4* __restrict__ houtb4,
    const float4* __restrict__ xin4, float4* __restrict__ out4)
{
    const int t = threadIdx.x & 3;
    for (int g = blockIdx.x * (TPB / 4) + (threadIdx.x >> 2); g < NN;
         g += GRID * (TPB / 4)) {
        const int s = row_ptr[g];
        const int e = row_ptr[g + 1];
        float acc[8] = {0.f, 0.f, 0.f, 0.f, 0.f, 0.f, 0.f, 0.f};

#define ACC8(W, V)                                                         \
        do {                                                               \
            acc[0] += (V) * __uint_as_float((W).x << 16);                  \
            acc[1] += (V) * __uint_as_float((W).x & 0xffff0000u);          \
            acc[2] += (V) * __uint_as_float((W).y << 16);                  \
            acc[3] += (V) * __uint_as_float((W).y & 0xffff0000u);          \
            acc[4] += (V) * __uint_as_float((W).z << 16);                  \
            acc[5] += (V) * __uint_as_float((W).z & 0xffff0000u);          \
            acc[6] += (V) * __uint_as_float((W).w << 16);                  \
            acc[7] += (V) * __uint_as_float((W).w & 0xffff0000u);          \
        } while (0)

        int i = s;
        for (; i + 4 <= e; i += 4) {
            int2 a0 = edges[i];
            int2 a1 = edges[i + 1];
            int2 a2 = edges[i + 2];
            int2 a3 = edges[i + 3];
            uint4 w0 = hb4[a0.x * 4 + t];
            uint4 w1 = hb4[a1.x * 4 + t];
            uint4 w2 = hb4[a2.x * 4 + t];
            uint4 w3 = hb4[a3.x * 4 + t];
            float v0 = __int_as_float(a0.y), v1 = __int_as_float(a1.y);
            float v2 = __int_as_float(a2.y), v3 = __int_as_float(a3.y);
            ACC8(w0, v0); ACC8(w1, v1); ACC8(w2, v2); ACC8(w3, v3);
        }
        for (; i < e; ++i) {
            int2 a0 = edges[i];
            uint4 w0 = hb4[a0.x * 4 + t];
            float v0 = __int_as_float(a0.y);
            ACC8(w0, v0);
        }
#undef ACC8

        if (MODE == 0 || MODE == 1) {
            uint4 p;
            p.x = f2bf(acc[0]) | (f2bf(acc[1]) << 16);
            p.y = f2bf(acc[2]) | (f2bf(acc[3]) << 16);
            p.z = f2bf(acc[4]) | (f2bf(acc[5]) << 16);
            p.w = f2bf(acc[6]) | (f2bf(acc[7]) << 16);
            houtb4[g * 4 + t] = p;
        }
        const int o = g * 8 + t * 2;
        float4 lo, hi;
        if (MODE == 0) {
            float4 x0 = xin4[o], x1 = xin4[o + 1];
            lo = make_float4(x0.x + acc[0], x0.y + acc[1], x0.z + acc[2], x0.w + acc[3]);
            hi = make_float4(x1.x + acc[4], x1.y + acc[5], x1.z + acc[6], x1.w + acc[7]);
        } else if (MODE == 1) {
            float4 o0 = out4[o], o1 = out4[o + 1];
            lo = make_float4(o0.x + acc[0], o0.y + acc[1], o0.z + acc[2], o0.w + acc[3]);
            hi = make_float4(o1.x + acc[4], o1.y + acc[5], o1.z + acc[6], o1.w + acc[7]);
        } else {
            float4 o0 = out4[o], o1 = out4[o + 1];
            lo = make_float4((o0.x + acc[0]) * 0.25f, (o0.y + acc[1]) * 0.25f,
                             (o0.z + acc[2]) * 0.25f, (o0.w + acc[3]) * 0.25f);
            hi = make_float4((o1.x + acc[4]) * 0.25f, (o1.y + acc[5]) * 0.25f,
                             (o1.z + acc[6]) * 0.25f, (o1.w + acc[7]) * 0.25f);
        }
        out4[o] = lo;
        out4[o + 1] = hi;
    }
}

// ---- the persistent mega-kernel ------------------------------------------

__global__ __launch_bounds__(TPB) void mega_kernel(
    const int* __restrict__ edge_row, const int* __restrict__ edge_col,
    const float* __restrict__ edge_val, const float* __restrict__ x,
    float* __restrict__ out,
    int* bar, int* bucket_tot, int* bucketbase, int* cursor, int* row_ptr,
    int2* tmp, int2* edges, unsigned* hb0, unsigned* hb1)
{
    __shared__ int s_cnt[NBKT];
    __shared__ int s_aux[NBKT];
    const int tid = threadIdx.x;
    const int blk = blockIdx.x;

    // ---- P1: chunk histogram (blocks < NCHUNK) + x -> bf16 cvt (all) ----
    if (blk < NCHUNK) {
        const int start = blk * CHUNK;
        const int n = min(CHUNK, NE - start);
        for (int k = tid; k < NBKT; k += TPB) s_cnt[k] = 0;
        __syncthreads();
        #pragma unroll
        for (int k = 0; k < CHUNK / TPB; k++) {
            int j = k * TPB + tid;
            if (j < n) atomicAdd(&s_cnt[edge_row[start + j] >> 7], 1);
        }
        __syncthreads();
        for (int k = tid; k < NBKT; k += TPB)
            if (s_cnt[k]) atomicAdd(&bucket_tot[k], s_cnt[k]);
    }
    {   // cvt: pack feats (2k,2k+1) into one u32 word of hb0
        const float2* x2 = (const float2*)x;
        for (int j = blk * TPB + tid; j < NN * DD / 2; j += GRID * TPB) {
            float2 f = x2[j];
            hb0[j] = f2bf(f.x) | (f2bf(f.y) << 16);
        }
    }
    grid_barrier(bar, 0);

    // ---- P2: exclusive scan of 782 bucket totals (block 0) --------------
    if (blk == 0) {
        int v = (tid < NBKT) ? bucket_tot[tid] : 0;
        int lane = tid & 63, w = tid >> 6;          // 16 waves
        int xx = v;
        #pragma unroll
        for (int off = 1; off < 64; off <<= 1) {
            int y = __shfl_up(xx, off, 64);
            if (lane >= off) xx += y;
        }
        if (lane == 63) s_aux[w] = xx;
        __syncthreads();
        if (w == 0 && lane < 16) {
            int y = s_aux[lane];
            #pragma unroll
            for (int off = 1; off < 16; off <<= 1) {
                int z = __shfl_up(y, off, 16);
                if ((lane & 15) >= off) y += z;
            }
            s_aux[lane] = y;                         // inclusive wave totals
        }
        __syncthreads();
        int wo = (w > 0) ? s_aux[w - 1] : 0;
        int excl = xx + wo - v;
        if (tid < NBKT) { bucketbase[tid] = excl; cursor[tid] = excl; }
        if (tid == NBKT) { bucketbase[NBKT] = NE; row_ptr[NN] = NE; }
    }
    grid_barrier(bar, 1);

    // ---- P3: multisplit scatter into bucket-contiguous tmp --------------
    if (blk < NCHUNK) {
        const int start = blk * CHUNK;
        const int n = min(CHUNK, NE - start);
        for (int k = tid; k < NBKT; k += TPB) s_cnt[k] = 0;
        __syncthreads();
        int rrow[CHUNK / TPB], rank[CHUNK / TPB];
        #pragma unroll
        for (int k = 0; k < CHUNK / TPB; k++) {
            int j = k * TPB + tid;
            int r = (j < n) ? edge_row[start + j] : -1;
            rrow[k] = r;
            rank[k] = (r >= 0) ? atomicAdd(&s_cnt[r >> 7], 1) : 0;
        }
        __syncthreads();
        for (int k = tid; k < NBKT; k += TPB)
            if (s_cnt[k]) s_aux[k] = atomicAdd(&cursor[k], s_cnt[k]);
        __syncthreads();
        #pragma unroll
        for (int k = 0; k < CHUNK / TPB; k++) {
            int j = k * TPB + tid;
            int r = rrow[k];
            if (r >= 0) {
                tmp[s_aux[r >> 7] + rank[k]] =
                    make_int2(((r & 127) << 17) | edge_col[start + j],
                              __float_as_int(edge_val[start + j]));
            }
        }
    }
    grid_barrier(bar, 2);

    // ---- P4: per-bucket row sort -> row_ptr + clean edges ---------------
    for (int b = blk; b < NBKT; b += GRID) {
        const int s = bucketbase[b];
        const int e = bucketbase[b + 1];
        if (tid < BROWS) s_cnt[tid] = 0;
        __syncthreads();
        int2 rc[3];
        #pragma unroll
        for (int k = 0; k < 3; k++) {
            int j = s + k * TPB + tid;
            rc[k] = (j < e) ? tmp[j] : make_int2(-1, 0);
            if (rc[k].x >= 0) atomicAdd(&s_cnt[rc[k].x >> 17], 1);
        }
        for (int j = s + 3 * TPB + tid; j < e; j += TPB)   // overflow (never)
            atomicAdd(&s_cnt[tmp[j].x >> 17], 1);
        __syncthreads();
        int v = 0, xx = 0;
        if (tid < BROWS) {
            v = s_cnt[tid];
            int lane = tid & 63;
            xx = v;
            #pragma unroll
            for (int off = 1; off < 64; off <<= 1) {
                int y = __shfl_up(xx, off, 64);
                if (lane >= off) xx += y;
            }
            if (lane == 63) s_aux[200 + (tid >> 6)] = xx;
        }
        __syncthreads();
        if (tid < BROWS) {
            int excl = xx + ((tid >> 6) ? s_aux[200] : 0) - v;
            s_aux[tid] = excl;                      // cur
            int r = b * BROWS + tid;
            if (r < NN) row_ptr[r] = s + excl;
        }
        __syncthreads();
        #pragma unroll
        for (int k = 0; k < 3; k++) {
            if (rc[k].x >= 0) {
                int pos = s + atomicAdd(&s_aux[rc[k].x >> 17], 1);
                edges[pos] = make_int2(rc[k].x & 0x1FFFF, rc[k].y);
            }
        }
        for (int j = s + 3 * TPB + tid; j < e; j += TPB) { // overflow (never)
            int2 rec = tmp[j];
            int pos = s + atomicAdd(&s_aux[rec.x >> 17], 1);
            edges[pos] = make_int2(rec.x & 0x1FFFF, rec.y);
        }
        __syncthreads();
    }
    grid_barrier(bar, 3);

    // ---- P5/P6/P7: the three propagation layers -------------------------
    spmm_phase<0>(row_ptr, edges, (const uint4*)hb0, (uint4*)hb1,
                  (const float4*)x, (float4*)out);
    grid_barrier(bar, 4);
    spmm_phase<1>(row_ptr, edges, (const uint4*)hb1, (uint4*)hb0,
                  (const float4*)x, (float4*)out);
    grid_barrier(bar, 5);
    spmm_phase<2>(row_ptr, edges, (const uint4*)hb0, (uint4*)hb1,
                  (const float4*)x, (float4*)out);
}

// ---- launch ---------------------------------------------------------------

extern "C" void kernel_launch(void* const* d_in, const int* in_sizes, int n_in,
                              void* d_out, int out_size, void* d_ws, size_t ws_size,
                              hipStream_t stream) {
    const int*   edge_row = (const int*)d_in[0];
    const int*   edge_col = (const int*)d_in[1];
    const float* edge_val = (const float*)d_in[2];
    const float* x        = (const float*)d_in[3];
    float* out = (float*)d_out;

    char* ws = (char*)d_ws;
    int*  bar        = (int*)ws;                          // 16 ints
    int*  bucket_tot = bar + 16;                          // 782
    int*  cursor     = bucket_tot + NBKT;                 // 782
    ws += ((16 + 2 * NBKT) * 4 + 511) & ~511ull;
    int*  bucketbase = (int*)ws;                          ws += ((size_t)(NBKT + 1) * 4 + 511) & ~511ull;
    int*  row_ptr    = (int*)ws;                          ws += ((size_t)(NN + 1) * 4 + 511) & ~511ull;
    int2* tmp        = (int2*)ws;                         ws += (size_t)NE * 8;       // 12.8 MB
    int2* edges      = (int2*)ws;                         ws += (size_t)NE * 8;       // 12.8 MB
    unsigned* hb0    = (unsigned*)ws;                     ws += (size_t)NN * DD * 2;  // 6.4 MB
    unsigned* hb1    = (unsigned*)ws;                     // 6.4 MB

    // zero barrier counters + bucket totals + cursors in one tiny memset
    hipMemsetAsync(bar, 0, (16 + 2 * NBKT) * sizeof(int), stream);

    mega_kernel<<<GRID, TPB, 0, stream>>>(edge_row, edge_col, edge_val, x, out,
                                          bar, bucket_tot, bucketbase, cursor,
                                          row_ptr, tmp, edges, hb0, hb1);
}

// Round 11
// 442.822 us; speedup vs baseline: 1.2534x; 1.2534x over previous
//
#include <hip/hip_runtime.h>

// LightGCN propagation on MI355X (gfx950).  MEASUREMENT ROUND.
// R7/R9/R10 all neutral-or-worse around 220 us and every kernel is below
// the harness's 43-us fill floor -> flying blind on the decomposition.
// This round amplifies hist / bucket_sort / spmm<0> by REP=8 internal
// repetitions (idempotent; asm memory clobber + no __restrict__ defeats
// cross-rep CSE) so each lands in the top-5 with its own dur + counters.
// Everything else is R9 verbatim (best: 219.5 us).

#define NN 100000
#define NE 1600000
#define DD 32
#define CHUNK 4096
#define NCHUNK ((NE + CHUNK - 1) / CHUNK)   // 391
#define BROWS 128
#define NBKT ((NN + BROWS - 1) / BROWS)     // 782
#define REP 8

__device__ __forceinline__ unsigned f2bf(float f) {
    unsigned u = __float_as_uint(f);
    return (u + 0x7fffu + ((u >> 16) & 1u)) >> 16;   // RNE
}

// ---- pass 1: bucket histogram (x REP, global adds on last rep only) ------

__global__ __launch_bounds__(1024) void hist_kernel(
    const int* row, int* bucket_tot)
{
    __shared__ int cnt[NBKT];
    const int tid = threadIdx.x;
    const int start = blockIdx.x * CHUNK;
    const int n = min(CHUNK, NE - start);
    for (int rep = 0; rep < REP; rep++) {
        asm volatile("" : : : "memory");
        for (int k = tid; k < NBKT; k += 1024) cnt[k] = 0;
        __syncthreads();
        #pragma unroll
        for (int k = 0; k < CHUNK / 1024; k++) {
            int j = k * 1024 + tid;
            if (j < n) atomicAdd(&cnt[row[start + j] >> 7], 1);
        }
        __syncthreads();
        if (rep == REP - 1) {
            for (int k = tid; k < NBKT; k += 1024)
                if (cnt[k]) atomicAdd(&bucket_tot[k], cnt[k]);
        }
        __syncthreads();
    }
}

// ---- pass 2: exclusive scan of 782 bucket totals -> base + cursors -------

__global__ __launch_bounds__(1024) void scan_kernel(
    const int* __restrict__ tot, int* __restrict__ bucketbase,
    int* __restrict__ cursor, int* __restrict__ row_ptr)
{
    const int tid = threadIdx.x;
    int v = (tid < NBKT) ? tot[tid] : 0;
    int lane = tid & 63, w = tid >> 6;          // 16 waves
    int x = v;
    #pragma unroll
    for (int off = 1; off < 64; off <<= 1) {
        int y = __shfl_up(x, off, 64);
        if (lane >= off) x += y;
    }
    __shared__ int wt[16];
    if (lane == 63) wt[w] = x;
    __syncthreads();
    if (w == 0 && lane < 16) {
        int y = wt[lane];
        #pragma unroll
        for (int off = 1; off < 16; off <<= 1) {
            int z = __shfl_up(y, off, 16);
            if ((lane & 15) >= off) y += z;
        }
        wt[lane] = y;                            // inclusive wave totals
    }
    __syncthreads();
    int wo = (w > 0) ? wt[w - 1] : 0;
    int excl = x + wo - v;
    if (tid < NBKT) { bucketbase[tid] = excl; cursor[tid] = excl; }
    if (tid == NBKT) { bucketbase[NBKT] = NE; row_ptr[NN] = NE; }
}

// ---- pass 3: multisplit scatter into bucket-contiguous layout ------------

__global__ __launch_bounds__(1024) void scatter_kernel(
    const int* __restrict__ row, const int* __restrict__ col,
    const float* __restrict__ val, int* __restrict__ cursor,
    int2* __restrict__ tmp)
{
    __shared__ int cnt[NBKT];
    __shared__ int gofs[NBKT];
    const int tid = threadIdx.x;
    const int start = blockIdx.x * CHUNK;
    const int n = min(CHUNK, NE - start);
    for (int k = tid; k < NBKT; k += 1024) cnt[k] = 0;
    __syncthreads();

    int rrow[CHUNK / 1024], rank[CHUNK / 1024];
    #pragma unroll
    for (int k = 0; k < CHUNK / 1024; k++) {
        int j = k * 1024 + tid;
        int r = (j < n) ? row[start + j] : -1;
        rrow[k] = r;
        rank[k] = (r >= 0) ? atomicAdd(&cnt[r >> 7], 1) : 0;
    }
    __syncthreads();
    for (int k = tid; k < NBKT; k += 1024)
        if (cnt[k]) gofs[k] = atomicAdd(&cursor[k], cnt[k]);
    __syncthreads();
    #pragma unroll
    for (int k = 0; k < CHUNK / 1024; k++) {
        int j = k * 1024 + tid;
        int r = rrow[k];
        if (r >= 0) {
            int b = r >> 7;
            tmp[gofs[b] + rank[k]] =
                make_int2(((r & 127) << 17) | col[start + j],
                          __float_as_int(val[start + j]));
        }
    }
}

// ---- pass 4: per-bucket row sort (x REP, full body; last rep wins) -------

__global__ __launch_bounds__(512) void bucket_sort_kernel(
    const int* bucketbase, const int2* tmp,
    int* row_ptr, int2* edges)
{
    __shared__ int cnt[BROWS];
    __shared__ int cur[BROWS];
    __shared__ int wt2[2];
    const int tid = threadIdx.x;
    const int b   = blockIdx.x;
    const int s   = bucketbase[b];
    const int e   = bucketbase[b + 1];

    for (int rep = 0; rep < REP; rep++) {
        asm volatile("" : : : "memory");
        if (tid < BROWS) cnt[tid] = 0;
        __syncthreads();

        int2 rc[5];
        #pragma unroll
        for (int k = 0; k < 5; k++) {
            int j = s + k * 512 + tid;
            rc[k] = (j < e) ? tmp[j] : make_int2(-1, 0);
            if (rc[k].x >= 0) atomicAdd(&cnt[rc[k].x >> 17], 1);
        }
        for (int j = s + 5 * 512 + tid; j < e; j += 512)   // overflow (rare)
            atomicAdd(&cnt[tmp[j].x >> 17], 1);
        __syncthreads();

        int v = 0, x = 0;
        if (tid < BROWS) {
            v = cnt[tid];
            int lane = tid & 63;
            x = v;
            #pragma unroll
            for (int off = 1; off < 64; off <<= 1) {
                int y = __shfl_up(x, off, 64);
                if (lane >= off) x += y;
            }
            if (lane == 63) wt2[tid >> 6] = x;
        }
        __syncthreads();
        if (tid < BROWS) {
            int excl = x + ((tid >> 6) ? wt2[0] : 0) - v;
            cur[tid] = excl;
            int r = b * BROWS + tid;
            if (r < NN) row_ptr[r] = s + excl;
        }
        __syncthreads();

        #pragma unroll
        for (int k = 0; k < 5; k++) {
            if (rc[k].x >= 0) {
                int pos = s + atomicAdd(&cur[rc[k].x >> 17], 1);
                edges[pos] = make_int2(rc[k].x & 0x1FFFF, rc[k].y);
            }
        }
        for (int j = s + 5 * 512 + tid; j < e; j += 512) { // overflow (rare)
            int2 rec = tmp[j];
            int pos = s + atomicAdd(&cur[rec.x >> 17], 1);
            edges[pos] = make_int2(rec.x & 0x1FFFF, rec.y);
        }
        __syncthreads();
    }
}

// ---- x -> bf16 table ------------------------------------------------------

__global__ __launch_bounds__(256) void cvt_kernel(
    const float2* __restrict__ xin2, unsigned* __restrict__ hb)
{
    int j = blockIdx.x * 256 + threadIdx.x;
    if (j >= NN * DD / 2) return;
    float2 f = xin2[j];
    hb[j] = f2bf(f.x) | (f2bf(f.y) << 16);
}

// ---- SpMM (R9): 4-lane group/row, bf16 gather. AMP!=0 only on MODE 0 -----

template <int MODE, int AMP>
__global__ __launch_bounds__(256) void spmm_kernel(
    const int* row_ptr, const int2* edges,
    const uint4* hb4, uint4* houtb4,
    const float4* xin4, float4* out4)
{
    const int g = blockIdx.x * 64 + (threadIdx.x >> 2);   // row
    if (g >= NN) return;
    const int t = threadIdx.x & 3;

    for (int rep = 0; rep < (AMP ? REP : 1); rep++) {
        asm volatile("" : : : "memory");
        const int s = row_ptr[g];
        const int e = row_ptr[g + 1];
        float acc[8] = {0.f, 0.f, 0.f, 0.f, 0.f, 0.f, 0.f, 0.f};

#define ACC8(W, V)                                                         \
        do {                                                               \
            acc[0] += (V) * __uint_as_float((W).x << 16);                  \
            acc[1] += (V) * __uint_as_float((W).x & 0xffff0000u);          \
            acc[2] += (V) * __uint_as_float((W).y << 16);                  \
            acc[3] += (V) * __uint_as_float((W).y & 0xffff0000u);          \
            acc[4] += (V) * __uint_as_float((W).z << 16);                  \
            acc[5] += (V) * __uint_as_float((W).z & 0xffff0000u);          \
            acc[6] += (V) * __uint_as_float((W).w << 16);                  \
            acc[7] += (V) * __uint_as_float((W).w & 0xffff0000u);          \
        } while (0)

        int i = s;
        for (; i + 4 <= e; i += 4) {
            int2 a0 = edges[i];
            int2 a1 = edges[i + 1];
            int2 a2 = edges[i + 2];
            int2 a3 = edges[i + 3];
            uint4 w0 = hb4[a0.x * 4 + t];
            uint4 w1 = hb4[a1.x * 4 + t];
            uint4 w2 = hb4[a2.x * 4 + t];
            uint4 w3 = hb4[a3.x * 4 + t];
            float v0 = __int_as_float(a0.y), v1 = __int_as_float(a1.y);
            float v2 = __int_as_float(a2.y), v3 = __int_as_float(a3.y);
            ACC8(w0, v0); ACC8(w1, v1); ACC8(w2, v2); ACC8(w3, v3);
        }
        for (; i < e; ++i) {
            int2 a0 = edges[i];
            uint4 w0 = hb4[a0.x * 4 + t];
            float v0 = __int_as_float(a0.y);
            ACC8(w0, v0);
        }
#undef ACC8

        if (MODE == 0 || MODE == 1) {
            uint4 p;
            p.x = f2bf(acc[0]) | (f2bf(acc[1]) << 16);
            p.y = f2bf(acc[2]) | (f2bf(acc[3]) << 16);
            p.z = f2bf(acc[4]) | (f2bf(acc[5]) << 16);
            p.w = f2bf(acc[6]) | (f2bf(acc[7]) << 16);
            houtb4[g * 4 + t] = p;
        }
        const int o = g * 8 + t * 2;
        float4 lo, hi;
        if (MODE == 0) {
            float4 x0 = xin4[o], x1 = xin4[o + 1];
            lo = make_float4(x0.x + acc[0], x0.y + acc[1], x0.z + acc[2], x0.w + acc[3]);
            hi = make_float4(x1.x + acc[4], x1.y + acc[5], x1.z + acc[6], x1.w + acc[7]);
        } else if (MODE == 1) {
            float4 o0 = out4[o], o1 = out4[o + 1];
            lo = make_float4(o0.x + acc[0], o0.y + acc[1], o0.z + acc[2], o0.w + acc[3]);
            hi = make_float4(o1.x + acc[4], o1.y + acc[5], o1.z + acc[6], o1.w + acc[7]);
        } else {
            float4 o0 = out4[o], o1 = out4[o + 1];
            lo = make_float4((o0.x + acc[0]) * 0.25f, (o0.y + acc[1]) * 0.25f,
                             (o0.z + acc[2]) * 0.25f, (o0.w + acc[3]) * 0.25f);
            hi = make_float4((o1.x + acc[4]) * 0.25f, (o1.y + acc[5]) * 0.25f,
                             (o1.z + acc[6]) * 0.25f, (o1.w + acc[7]) * 0.25f);
        }
        out4[o] = lo;
        out4[o + 1] = hi;
    }
}

// ---- launch ---------------------------------------------------------------

extern "C" void kernel_launch(void* const* d_in, const int* in_sizes, int n_in,
                              void* d_out, int out_size, void* d_ws, size_t ws_size,
                              hipStream_t stream) {
    const int*   edge_row = (const int*)d_in[0];
    const int*   edge_col = (const int*)d_in[1];
    const float* edge_val = (const float*)d_in[2];
    const float* x        = (const float*)d_in[3];
    float* out = (float*)d_out;

    char* ws = (char*)d_ws;
    int*  bucket_tot = (int*)ws;                          ws += 4096;
    int*  bucketbase = (int*)ws;                          ws += 4096;
    int*  cursor     = (int*)ws;                          ws += 4096;
    int*  row_ptr    = (int*)ws;                          ws += ((size_t)(NN + 1) * 4 + 511) & ~511ull;
    int2* tmp        = (int2*)ws;                         ws += (size_t)NE * 8 + 64;  // 12.8 MB
    int2* edges      = (int2*)ws;                         ws += (size_t)NE * 8 + 64;  // 12.8 MB
    unsigned* hb0    = (unsigned*)ws;                     ws += (size_t)NN * DD * 2;  // 6.4 MB
    unsigned* hb1    = (unsigned*)ws;                     ws += (size_t)NN * DD * 2;  // 6.4 MB

    hipMemsetAsync(bucket_tot, 0, NBKT * sizeof(int), stream);
    hist_kernel       <<<NCHUNK, 1024, 0, stream>>>(edge_row, bucket_tot);
    scan_kernel       <<<1, 1024, 0, stream>>>(bucket_tot, bucketbase, cursor, row_ptr);
    scatter_kernel    <<<NCHUNK, 1024, 0, stream>>>(edge_row, edge_col, edge_val,
                                                    cursor, tmp);
    bucket_sort_kernel<<<NBKT, 512, 0, stream>>>(bucketbase, tmp, row_ptr, edges);
    cvt_kernel        <<<(NN * DD / 2 + 255) / 256, 256, 0, stream>>>(
                        (const float2*)x, hb0);

    dim3 sp_grid((NN + 63) / 64);   // 1563 blocks, 4 lanes/row, 64 rows/block
    spmm_kernel<0, 1><<<sp_grid, 256, 0, stream>>>(row_ptr, edges,
        (const uint4*)hb0, (uint4*)hb1, (const float4*)x, (float4*)out);
    spmm_kernel<1, 0><<<sp_grid, 256, 0, stream>>>(row_ptr, edges,
        (const uint4*)hb1, (uint4*)hb0, (const float4*)x, (float4*)out);
    spmm_kernel<2, 0><<<sp_grid, 256, 0, stream>>>(row_ptr, edges,
        (const uint4*)hb0, (uint4*)hb1, (const float4*)x, (float4*)out);
}

// Round 12
// 227.666 us; speedup vs baseline: 2.4378x; 1.9451x over previous
//
#include <hip/hip_runtime.h>
#include <hip/hip_fp16.h>

// LightGCN propagation on MI355X (gfx950).
//   h_{k+1}[r,:] = sum_{e: row[e]==r} val[e] * h_k[col[e],:]   D=32
//   out = (x + h1 + h2 + h3) / 4
//
// Round 12 (from R11's amplification decomposition: spmm ~25.5 us/layer,
// hist+sort ~6.3 us combined, rest is scatter + node gaps + graph fixed
// cost):
//   1) 9 -> 7 dispatch nodes: cvt folded into hist (grid-stride tail),
//      scan folded into hist's LAST-BLOCK ticket (device-scope acq_rel;
//      last of 391 blocks runs the 782-entry scan inline).
//   2) 4 B edge records for the spmm stream: col(17b) | sign-less
//      fp16 val(15b)  (val in [0,1) -> sign bit free). Saves ~25 MB of
//      sort-write + 3x spmm-read traffic; val rounding 2^-12 << bf16 2^-9.
// spmm inner loop is R9's proven 4-lane bf16-gather (insensitive to
// record staging per R7, so decode cost is nil).

#define NN 100000
#define NE 1600000
#define DD 32
#define CHUNK 4096
#define NCHUNK ((NE + CHUNK - 1) / CHUNK)   // 391
#define BROWS 128
#define NBKT ((NN + BROWS - 1) / BROWS)     // 782

__device__ __forceinline__ unsigned f2bf(float f) {
    unsigned u = __float_as_uint(f);
    return (u + 0x7fffu + ((u >> 16) & 1u)) >> 16;   // RNE
}

// ---- K1: hist + cvt + last-block scan ------------------------------------

__global__ __launch_bounds__(1024) void hist_cvt_scan_kernel(
    const int* __restrict__ row, const float2* __restrict__ x2,
    int* __restrict__ bucket_tot, unsigned* __restrict__ hb0,
    int* __restrict__ ticket, int* __restrict__ bucketbase,
    int* __restrict__ cursor, int* __restrict__ row_ptr)
{
    __shared__ int cnt[NBKT];
    __shared__ int s_tick;
    const int tid = threadIdx.x;
    const int start = blockIdx.x * CHUNK;
    const int n = min(CHUNK, NE - start);

    // hist phase
    for (int k = tid; k < NBKT; k += 1024) cnt[k] = 0;
    __syncthreads();
    #pragma unroll
    for (int k = 0; k < CHUNK / 1024; k++) {
        int j = k * 1024 + tid;
        if (j < n) atomicAdd(&cnt[row[start + j] >> 7], 1);
    }
    __syncthreads();
    for (int k = tid; k < NBKT; k += 1024)
        if (cnt[k]) atomicAdd(&bucket_tot[k], cnt[k]);

    // cvt phase: pack feats (2k,2k+1) of x into bf16 words of hb0
    for (int j = blockIdx.x * 1024 + tid; j < NN * DD / 2; j += NCHUNK * 1024) {
        float2 f = x2[j];
        hb0[j] = f2bf(f.x) | (f2bf(f.y) << 16);
    }

    // ticket: last block to finish runs the bucket scan
    __syncthreads();
    if (tid == 0) {
        __threadfence();
        s_tick = __hip_atomic_fetch_add(ticket, 1, __ATOMIC_ACQ_REL,
                                        __HIP_MEMORY_SCOPE_AGENT);
    }
    __syncthreads();
    if (s_tick != NCHUNK - 1) return;
    __threadfence();

    // scan phase (one 1024-thread block, 782 entries)
    int v = (tid < NBKT) ? bucket_tot[tid] : 0;
    int lane = tid & 63, w = tid >> 6;          // 16 waves
    int x = v;
    #pragma unroll
    for (int off = 1; off < 64; off <<= 1) {
        int y = __shfl_up(x, off, 64);
        if (lane >= off) x += y;
    }
    __shared__ int wt[16];
    if (lane == 63) wt[w] = x;
    __syncthreads();
    if (w == 0 && lane < 16) {
        int y = wt[lane];
        #pragma unroll
        for (int off = 1; off < 16; off <<= 1) {
            int z = __shfl_up(y, off, 16);
            if ((lane & 15) >= off) y += z;
        }
        wt[lane] = y;                            // inclusive wave totals
    }
    __syncthreads();
    int wo = (w > 0) ? wt[w - 1] : 0;
    int excl = x + wo - v;
    if (tid < NBKT) { bucketbase[tid] = excl; cursor[tid] = excl; }
    if (tid == NBKT) { bucketbase[NBKT] = NE; row_ptr[NN] = NE; }
}

// ---- K2: multisplit scatter into bucket-contiguous tmp (8 B records) -----
// tmp record: .x = ((row & 127) << 17) | col,  .y = val fp32 bits

__global__ __launch_bounds__(1024) void scatter_kernel(
    const int* __restrict__ row, const int* __restrict__ col,
    const float* __restrict__ val, int* __restrict__ cursor,
    int2* __restrict__ tmp)
{
    __shared__ int cnt[NBKT];
    __shared__ int gofs[NBKT];
    const int tid = threadIdx.x;
    const int start = blockIdx.x * CHUNK;
    const int n = min(CHUNK, NE - start);
    for (int k = tid; k < NBKT; k += 1024) cnt[k] = 0;
    __syncthreads();

    int rrow[CHUNK / 1024], rank[CHUNK / 1024];
    #pragma unroll
    for (int k = 0; k < CHUNK / 1024; k++) {
        int j = k * 1024 + tid;
        int r = (j < n) ? row[start + j] : -1;
        rrow[k] = r;
        rank[k] = (r >= 0) ? atomicAdd(&cnt[r >> 7], 1) : 0;
    }
    __syncthreads();
    for (int k = tid; k < NBKT; k += 1024)
        if (cnt[k]) gofs[k] = atomicAdd(&cursor[k], cnt[k]);
    __syncthreads();
    #pragma unroll
    for (int k = 0; k < CHUNK / 1024; k++) {
        int j = k * 1024 + tid;
        int r = rrow[k];
        if (r >= 0) {
            int b = r >> 7;
            tmp[gofs[b] + rank[k]] =
                make_int2(((r & 127) << 17) | col[start + j],
                          __float_as_int(val[start + j]));
        }
    }
}

// ---- K3: per-bucket row sort -> row_ptr + packed 4 B edges ---------------
// edge record: (col << 15) | (fp16(val) & 0x7FFF)   (val >= 0, sign free)

__global__ __launch_bounds__(512) void bucket_sort_kernel(
    const int* __restrict__ bucketbase, const int2* __restrict__ tmp,
    int* __restrict__ row_ptr, unsigned* __restrict__ edges)
{
    __shared__ int cnt[BROWS];
    __shared__ int cur[BROWS];
    __shared__ int wt2[2];
    const int tid = threadIdx.x;
    const int b   = blockIdx.x;
    const int s   = bucketbase[b];
    const int e   = bucketbase[b + 1];

    if (tid < BROWS) cnt[tid] = 0;
    __syncthreads();

    int2 rc[5];
    #pragma unroll
    for (int k = 0; k < 5; k++) {
        int j = s + k * 512 + tid;
        rc[k] = (j < e) ? tmp[j] : make_int2(-1, 0);
        if (rc[k].x >= 0) atomicAdd(&cnt[rc[k].x >> 17], 1);
    }
    for (int j = s + 5 * 512 + tid; j < e; j += 512)       // overflow (rare)
        atomicAdd(&cnt[tmp[j].x >> 17], 1);
    __syncthreads();

    int v = 0, x = 0;
    if (tid < BROWS) {
        v = cnt[tid];
        int lane = tid & 63;
        x = v;
        #pragma unroll
        for (int off = 1; off < 64; off <<= 1) {
            int y = __shfl_up(x, off, 64);
            if (lane >= off) x += y;
        }
        if (lane == 63) wt2[tid >> 6] = x;
    }
    __syncthreads();
    if (tid < BROWS) {
        int excl = x + ((tid >> 6) ? wt2[0] : 0) - v;
        cur[tid] = excl;
        int r = b * BROWS + tid;
        if (r < NN) row_ptr[r] = s + excl;
    }
    __syncthreads();

    #pragma unroll
    for (int k = 0; k < 5; k++) {
        if (rc[k].x >= 0) {
            int pos = s + atomicAdd(&cur[rc[k].x >> 17], 1);
            unsigned hv = __half_as_ushort(__float2half(__int_as_float(rc[k].y)));
            edges[pos] = ((unsigned)(rc[k].x & 0x1FFFF) << 15) | (hv & 0x7FFFu);
        }
    }
    for (int j = s + 5 * 512 + tid; j < e; j += 512) {     // overflow (rare)
        int2 rec = tmp[j];
        int pos = s + atomicAdd(&cur[rec.x >> 17], 1);
        unsigned hv = __half_as_ushort(__float2half(__int_as_float(rec.y)));
        edges[pos] = ((unsigned)(rec.x & 0x1FFFF) << 15) | (hv & 0x7FFFu);
    }
}

// ---- SpMM (R9): 4-lane group/row, bf16 uint4 gather, 4 B records ---------
// MODE 0: houtb = bf16(A x) ; out  = x + A x
// MODE 1: houtb = bf16(A h) ; out += A h
// MODE 2: out = (out + A h) * 0.25

template <int MODE>
__global__ __launch_bounds__(256) void spmm_kernel(
    const int* __restrict__ row_ptr, const unsigned* __restrict__ edges,
    const uint4* __restrict__ hb4, uint4* __restrict__ houtb4,
    const float4* __restrict__ xin4, float4* __restrict__ out4)
{
    const int g = blockIdx.x * 64 + (threadIdx.x >> 2);   // row
    if (g >= NN) return;
    const int t = threadIdx.x & 3;
    const int s = row_ptr[g];
    const int e = row_ptr[g + 1];

    float acc[8] = {0.f, 0.f, 0.f, 0.f, 0.f, 0.f, 0.f, 0.f};

#define DECV(A) __half2float(__ushort_as_half((unsigned short)((A) & 0x7FFFu)))
#define ACC8(W, V)                                                         \
    do {                                                                   \
        acc[0] += (V) * __uint_as_float((W).x << 16);                      \
        acc[1] += (V) * __uint_as_float((W).x & 0xffff0000u);              \
        acc[2] += (V) * __uint_as_float((W).y << 16);                      \
        acc[3] += (V) * __uint_as_float((W).y & 0xffff0000u);              \
        acc[4] += (V) * __uint_as_float((W).z << 16);                      \
        acc[5] += (V) * __uint_as_float((W).z & 0xffff0000u);              \
        acc[6] += (V) * __uint_as_float((W).w << 16);                      \
        acc[7] += (V) * __uint_as_float((W).w & 0xffff0000u);              \
    } while (0)

    int i = s;
    for (; i + 4 <= e; i += 4) {                 // 4 gathers in flight
        unsigned a0 = edges[i];
        unsigned a1 = edges[i + 1];
        unsigned a2 = edges[i + 2];
        unsigned a3 = edges[i + 3];
        uint4 w0 = hb4[(a0 >> 15) * 4 + t];
        uint4 w1 = hb4[(a1 >> 15) * 4 + t];
        uint4 w2 = hb4[(a2 >> 15) * 4 + t];
        uint4 w3 = hb4[(a3 >> 15) * 4 + t];
        float v0 = DECV(a0), v1 = DECV(a1);
        float v2 = DECV(a2), v3 = DECV(a3);
        ACC8(w0, v0); ACC8(w1, v1); ACC8(w2, v2); ACC8(w3, v3);
    }
    for (; i < e; ++i) {
        unsigned a0 = edges[i];
        uint4 w0 = hb4[(a0 >> 15) * 4 + t];
        float v0 = DECV(a0);
        ACC8(w0, v0);
    }
#undef ACC8
#undef DECV

    if (MODE == 0 || MODE == 1) {
        uint4 p;
        p.x = f2bf(acc[0]) | (f2bf(acc[1]) << 16);
        p.y = f2bf(acc[2]) | (f2bf(acc[3]) << 16);
        p.z = f2bf(acc[4]) | (f2bf(acc[5]) << 16);
        p.w = f2bf(acc[6]) | (f2bf(acc[7]) << 16);
        houtb4[g * 4 + t] = p;
    }
    const int o = g * 8 + t * 2;                 // two float4s per lane
    float4 lo, hi;
    if (MODE == 0) {
        float4 x0 = xin4[o], x1 = xin4[o + 1];
        lo = make_float4(x0.x + acc[0], x0.y + acc[1], x0.z + acc[2], x0.w + acc[3]);
        hi = make_float4(x1.x + acc[4], x1.y + acc[5], x1.z + acc[6], x1.w + acc[7]);
    } else if (MODE == 1) {
        float4 o0 = out4[o], o1 = out4[o + 1];
        lo = make_float4(o0.x + acc[0], o0.y + acc[1], o0.z + acc[2], o0.w + acc[3]);
        hi = make_float4(o1.x + acc[4], o1.y + acc[5], o1.z + acc[6], o1.w + acc[7]);
    } else {
        float4 o0 = out4[o], o1 = out4[o + 1];
        lo = make_float4((o0.x + acc[0]) * 0.25f, (o0.y + acc[1]) * 0.25f,
                         (o0.z + acc[2]) * 0.25f, (o0.w + acc[3]) * 0.25f);
        hi = make_float4((o1.x + acc[4]) * 0.25f, (o1.y + acc[5]) * 0.25f,
                         (o1.z + acc[6]) * 0.25f, (o1.w + acc[7]) * 0.25f);
    }
    out4[o] = lo;
    out4[o + 1] = hi;
}

// ---- launch ---------------------------------------------------------------

extern "C" void kernel_launch(void* const* d_in, const int* in_sizes, int n_in,
                              void* d_out, int out_size, void* d_ws, size_t ws_size,
                              hipStream_t stream) {
    const int*   edge_row = (const int*)d_in[0];
    const int*   edge_col = (const int*)d_in[1];
    const float* edge_val = (const float*)d_in[2];
    const float* x        = (const float*)d_in[3];
    float* out = (float*)d_out;

    char* ws = (char*)d_ws;
    int*  bucket_tot = (int*)ws;                          // 782 ints
    int*  ticket     = bucket_tot + NBKT;                 // 1 int (memset w/ tot)
    ws += ((size_t)(NBKT + 1) * 4 + 511) & ~511ull;
    int*  bucketbase = (int*)ws;                          ws += ((size_t)(NBKT + 1) * 4 + 511) & ~511ull;
    int*  cursor     = (int*)ws;                          ws += ((size_t)NBKT * 4 + 511) & ~511ull;
    int*  row_ptr    = (int*)ws;                          ws += ((size_t)(NN + 1) * 4 + 511) & ~511ull;
    int2* tmp        = (int2*)ws;                         ws += (size_t)NE * 8 + 64;  // 12.8 MB
    unsigned* edges  = (unsigned*)ws;                     ws += (size_t)NE * 4 + 64;  // 6.4 MB
    unsigned* hb0    = (unsigned*)ws;                     ws += (size_t)NN * DD * 2;  // 6.4 MB
    unsigned* hb1    = (unsigned*)ws;                     ws += (size_t)NN * DD * 2;  // 6.4 MB

    hipMemsetAsync(bucket_tot, 0, (NBKT + 1) * sizeof(int), stream);
    hist_cvt_scan_kernel<<<NCHUNK, 1024, 0, stream>>>(
        edge_row, (const float2*)x, bucket_tot, hb0, ticket,
        bucketbase, cursor, row_ptr);
    scatter_kernel<<<NCHUNK, 1024, 0, stream>>>(edge_row, edge_col, edge_val,
                                                cursor, tmp);
    bucket_sort_kernel<<<NBKT, 512, 0, stream>>>(bucketbase, tmp, row_ptr, edges);

    dim3 sp_grid((NN + 63) / 64);   // 1563 blocks, 4 lanes/row, 64 rows/block
    spmm_kernel<0><<<sp_grid, 256, 0, stream>>>(row_ptr, edges,
        (const uint4*)hb0, (uint4*)hb1, (const float4*)x, (float4*)out);
    spmm_kernel<1><<<sp_grid, 256, 0, stream>>>(row_ptr, edges,
        (const uint4*)hb1, (uint4*)hb0, (const float4*)x, (float4*)out);
    spmm_kernel<2><<<sp_grid, 256, 0, stream>>>(row_ptr, edges,
        (const uint4*)hb0, (uint4*)hb1, (const float4*)x, (float4*)out);
}